// Round 9
// baseline (340.313 us; speedup 1.0000x reference)
//
#include <hip/hip_runtime.h>
#include <math.h>

#define D_MODEL 768
#define D_STATE 16
#define D_CONV  4
#define D_INNER 1536
#define BATCH   2
#define SEQ     512
#define M_ROWS  (BATCH * SEQ)            // 1024
#define N_XZ    (2 * D_INNER)            // 3072
#define N_XDBL  (D_INNER + 2 * D_STATE)  // 1568

typedef short  short8 __attribute__((ext_vector_type(8)));
typedef float  f32x4  __attribute__((ext_vector_type(4)));
typedef unsigned short ushort_t;
typedef ushort_t ushort8_t __attribute__((ext_vector_type(8)));

// ---- manual bf16 helpers (RNE), raw ushort storage ----
__device__ __forceinline__ ushort_t f2bf(float f) {
    unsigned int u = __float_as_uint(f);
    return (ushort_t)((u + 0x7fffu + ((u >> 16) & 1u)) >> 16);
}
__device__ __forceinline__ float bf2f(ushort_t s) {
    return __uint_as_float((unsigned int)s << 16);
}
__device__ __forceinline__ void split1(float x, ushort_t& h, ushort_t& l) {
    h = f2bf(x);
    l = f2bf(x - bf2f(h));
}
// split 8 consecutive fp32 -> interleaved [h0..h7][l0..l7] (32 B) at d
__device__ __forceinline__ void split8(const float* s, ushort_t* d) {
    ushort8_t h, l;
#pragma unroll
    for (int j = 0; j < 8; ++j) { ushort_t hh, ll; split1(s[j], hh, ll); h[j] = hh; l[j] = ll; }
    *(ushort8_t*)(d)     = h;
    *(ushort8_t*)(d + 8) = l;
}

// ---------------------------------------------------------------------------
// Fused split: x -> xs, W_in -> w1, W_x -> w2 (interleaved h|l layout).
// ---------------------------------------------------------------------------
#define SX  (M_ROWS * D_MODEL)
#define SW1 (N_XZ * D_MODEL)
#define SW2 (N_XDBL * D_INNER)
__global__ __launch_bounds__(256) void split3_kernel(
    const float* __restrict__ x, const float* __restrict__ win,
    const float* __restrict__ wx,
    ushort_t* __restrict__ xs, ushort_t* __restrict__ w1, ushort_t* __restrict__ w2)
{
    long i = ((long)blockIdx.x * 256 + threadIdx.x) * 8;
    const float* src; ushort_t* dst; long base;
    if (i < SX)            { src = x;   dst = xs; base = i; }
    else if (i < SX + SW1) { src = win; dst = w1; base = i - SX; }
    else                   { src = wx;  dst = w2; base = i - SX - SW1; }
    float v[8];
    *(float4*)(v)     = *(const float4*)(src + base);
    *(float4*)(v + 4) = *(const float4*)(src + base + 4);
    split8(v, dst + 2 * base);
}

// single-tensor split (interleaved), 8 elems/thread
__global__ __launch_bounds__(256) void split_kernel(
    const float* __restrict__ in, ushort_t* __restrict__ outp, long n)
{
    long i = ((long)blockIdx.x * 256 + threadIdx.x) * 8;
    if (i >= n) return;
    float v[8];
    *(float4*)(v)     = *(const float4*)(in + i);
    *(float4*)(v + 4) = *(const float4*)(in + i + 4);
    split8(v, outp + 2 * i);
}

// ---------------------------------------------------------------------------
// Split-bf16 MFMA GEMM — one wave per block, 64x64 tile, no LDS, no barriers.
// DEPTH-4 rolling register pipeline: slot j's reload is issued 3 MFMA-blocks
// (~700 cyc) before consumption, keeping ~48-64 loads in flight per wave
// (vs depth-2's ~16-32) to cover L3/HBM latency. ~350 VGPRs @ 1 wave/EU.
// Operands interleaved h|l: row r, elem k -> ushort off r*2K + 2k (h), +8 (l).
// XCD-compact swizzle (verified R8: FETCH 68->20.6 MB).
// NP = K-chunks (grid.z); chunk z stores fp32 partial to Cz.
// ---------------------------------------------------------------------------
template <int NP>
__global__ __launch_bounds__(64, 1) void gemm_mfma(
    const ushort_t* __restrict__ A, int lda,   // lda = K in elems
    const ushort_t* __restrict__ B, int ldb,
    float* __restrict__ C0, float* __restrict__ C1,
    float* __restrict__ C2, float* __restrict__ C3, int ldc,
    int N, int kc)
{
    const int Gx = gridDim.x, Gy = gridDim.y;
    const int T = Gx * Gy * gridDim.z;
    const int f = blockIdx.x + Gx * (blockIdx.y + Gy * blockIdx.z);
    const int R = T >> 3;
    const int g = (f & 7) * R + (f >> 3);
    const int bx = g % Gx;
    const int yz = g / Gx;
    const int by = yz % Gy;
    const int z  = yz / Gy;
    float* __restrict__ C = (NP <= 1 || z == 0) ? C0 :
                            (z == 1) ? C1 : (NP >= 3 && z == 2) ? C2 : C3;

    const int lane = threadIdx.x;
    const int bm = by * 64;
    const int bn = bx * 64;
    const int lr = lane & 15;
    const int lq = lane >> 4;
    const long kabs = (long)z * kc + lq * 8;

    long oA[4], oB[4];
#pragma unroll
    for (int i = 0; i < 4; ++i) {
        oA[i] = (long)(bm + i * 16 + lr) * (2 * lda) + 2 * kabs;
        int rB = bn + i * 16 + lr;
        if (rB >= N) rB = N - 1;               // clamp: in-buffer, discarded
        oB[i] = (long)rB * (2 * ldb) + 2 * kabs;
    }

    f32x4 acc[4][4] = {};
    short8 ah[4][4], al[4][4], bh[4][4], bl[4][4];   // [slot][row]

    auto loadslot = [&](int slot, int s) {
        const int kk2 = s * 64;                      // ushort offset = 2*(32k)
#pragma unroll
        for (int i = 0; i < 4; ++i) {
            ah[slot][i] = *(const short8*)(A + oA[i] + kk2);
            al[slot][i] = *(const short8*)(A + oA[i] + kk2 + 8);
            bh[slot][i] = *(const short8*)(B + oB[i] + kk2);
            bl[slot][i] = *(const short8*)(B + oB[i] + kk2 + 8);
        }
    };
    auto mfmaslot = [&](int slot) {
#pragma unroll
        for (int mt = 0; mt < 4; ++mt)
#pragma unroll
            for (int nt = 0; nt < 4; ++nt) {
                acc[mt][nt] = __builtin_amdgcn_mfma_f32_16x16x32_bf16(al[slot][mt], bh[slot][nt], acc[mt][nt], 0, 0, 0);
                acc[mt][nt] = __builtin_amdgcn_mfma_f32_16x16x32_bf16(ah[slot][mt], bl[slot][nt], acc[mt][nt], 0, 0, 0);
                acc[mt][nt] = __builtin_amdgcn_mfma_f32_16x16x32_bf16(ah[slot][mt], bh[slot][nt], acc[mt][nt], 0, 0, 0);
            }
    };

    const int nSets = kc >> 5;                 // sets of k=32; users: 24/16/12/12
    loadslot(0, 0); loadslot(1, 1); loadslot(2, 2); loadslot(3, 3);
    for (int s = 0; s < nSets; s += 4) {
#pragma unroll
        for (int j = 0; j < 4; ++j) {
            mfmaslot(j);
            if (s + 4 + j < nSets) loadslot(j, s + 4 + j);
        }
    }

    // C/D layout: col = lane&15, row = (lane>>4)*4 + reg  [m89/m91]
    const int col0 = lane & 15;
    const int quad = lane >> 4;
#pragma unroll
    for (int mt = 0; mt < 4; ++mt)
#pragma unroll
        for (int nt = 0; nt < 4; ++nt)
#pragma unroll
            for (int r = 0; r < 4; ++r) {
                int row = bm + mt * 16 + quad * 4 + r;
                int col = bn + nt * 16 + col0;
                if (col >= N) continue;
                C[(long)row * ldc + col] = acc[mt][nt][r];
            }
}

// ---------------------------------------------------------------------------
// GEMM3 epilogue (3 partials): f = p0+p1+p2 -> xd interleaved split; cols >=
// 1536 also stored transposed fp32 into BCT. p2 aliases xd region
// (same-thread read-before-write).
// ---------------------------------------------------------------------------
__global__ __launch_bounds__(256) void ep_xdbl_kernel(
    const float* __restrict__ p0, const float* __restrict__ p1,
    const float* p2, ushort_t* xd, float* __restrict__ BCT)
{
    long i = ((long)blockIdx.x * 256 + threadIdx.x) * 8;
    if (i >= (long)M_ROWS * N_XDBL) return;
    int row = (int)(i / N_XDBL);
    int col = (int)(i - (long)row * N_XDBL);    // multiple of 8
    float f[8];
#pragma unroll
    for (int j = 0; j < 8; ++j) f[j] = p0[i + j] + p1[i + j] + p2[i + j];
    split8(f, xd + 2 * i);
    if (col >= D_INNER) {
#pragma unroll
        for (int j = 0; j < 8; ++j)
            BCT[(long)(col + j - D_INNER) * M_ROWS + row] = f[j];
    }
}

// ---------------------------------------------------------------------------
// GEMM4 epilogue (4 partials): deltaT = softplus(sum + b_dt[row]).
// deltaT aliases p1 (same-index elementwise).
// ---------------------------------------------------------------------------
__global__ __launch_bounds__(256) void ep_softplus_kernel(
    const float* p0, const float* p1, const float* p2, const float* p3,
    const float* __restrict__ b_dt, float* deltaT)
{
    long i = ((long)blockIdx.x * 256 + threadIdx.x) * 8;
    if (i >= (long)D_INNER * M_ROWS) return;
    float b = b_dt[i >> 10];
    float o[8];
#pragma unroll
    for (int j = 0; j < 8; ++j) {
        float v = p0[i+j] + p1[i+j] + p2[i+j] + p3[i+j] + b;
        o[j] = fmaxf(v, 0.f) + log1pf(expf(-fabsf(v)));
    }
    *(float4*)(deltaT + i)     = *(float4*)(o);
    *(float4*)(deltaT + i + 4) = *(float4*)(o + 4);
}

// ---------------------------------------------------------------------------
// GEMM6 epilogue: out = p0+p1+p2+p3
// ---------------------------------------------------------------------------
__global__ __launch_bounds__(256) void ep_merge_kernel(
    const float* __restrict__ p0, const float* __restrict__ p1,
    const float* __restrict__ p2, const float* __restrict__ p3,
    float* __restrict__ out)
{
    long i = ((long)blockIdx.x * 256 + threadIdx.x) * 8;
    if (i >= (long)M_ROWS * D_MODEL) return;
    float o[8];
#pragma unroll
    for (int j = 0; j < 8; ++j) o[j] = p0[i+j] + p1[i+j] + p2[i+j] + p3[i+j];
    *(float4*)(out + i)     = *(float4*)(o);
    *(float4*)(out + i + 4) = *(float4*)(o + 4);
}

// ---------------------------------------------------------------------------
// Depthwise causal conv (width 4) + bias + SiLU.
// ---------------------------------------------------------------------------
__global__ __launch_bounds__(256) void conv_silu_kernel(
    const float* __restrict__ xz,
    const float* __restrict__ conv_w,
    const float* __restrict__ conv_b,
    float* __restrict__ xconvT,
    float* __restrict__ zsiluT,
    ushort_t* __restrict__ xc)
{
    int idx = blockIdx.x * blockDim.x + threadIdx.x;
    if (idx >= M_ROWS * D_INNER) return;
    int d = idx % D_INNER;
    int r = idx / D_INNER;
    int l = r % SEQ;
    float acc = conv_b[d];
#pragma unroll
    for (int k = 0; k < D_CONV; ++k) {
        if (l - (D_CONV - 1) + k >= 0)
            acc = fmaf(conv_w[d * D_CONV + k],
                       xz[(long)(r - (D_CONV - 1 - k)) * N_XZ + d], acc);
    }
    float s = acc / (1.f + expf(-acc));
    xconvT[(long)d * M_ROWS + r] = s;
    ushort_t h, lo;
    split1(s, h, lo);
    long off = (long)r * (2 * D_INNER) + ((d >> 3) * 16 + (d & 7));
    xc[off]     = h;
    xc[off + 8] = lo;
    float zv = xz[(long)r * N_XZ + D_INNER + d];
    zsiluT[(long)d * M_ROWS + r] = zv / (1.f + expf(-zv));
}

// ---------------------------------------------------------------------------
// Wave-per-(b,d) register scan. No LDS, no barriers. (verified R4-R8)
// ---------------------------------------------------------------------------
__global__ __launch_bounds__(256) void scan_kernel(
    const float* __restrict__ deltaT,
    const float* __restrict__ xconvT,
    const float* __restrict__ zsiluT,
    const float* __restrict__ BCT,     // (32, 1024)
    const float* __restrict__ A_log,
    const float* __restrict__ Dp,
    float* __restrict__ uT)
{
    const int bid = blockIdx.x;
    const int b   = bid / (D_INNER / 4);
    const int dg  = bid % (D_INNER / 4);
    const int tid = threadIdx.x;
    const int w   = tid >> 6;
    const int t   = tid & 63;
    const int d   = dg * 4 + w;
    const int base = b * SEQ;
    const int l0 = 8 * t;

    float dl[8], xr[8], yac[8];
#pragma unroll
    for (int i = 0; i < 8; ++i) {
        dl[i] = deltaT[(long)d * M_ROWS + base + l0 + i];
        xr[i] = xconvT[(long)d * M_ROWS + base + l0 + i];
        yac[i] = 0.f;
    }

    for (int n = 0; n < D_STATE; ++n) {
        const float Adn = -expf(A_log[d * D_STATE + n]);
        const float4* Bp = (const float4*)(BCT + (long)n * M_ROWS + base + l0);
        float4 b0 = Bp[0], b1 = Bp[1];
        float Bv[8] = {b0.x, b0.y, b0.z, b0.w, b1.x, b1.y, b1.z, b1.w};
        float c[8], v[8];
#pragma unroll
        for (int i = 0; i < 8; ++i) {
            c[i] = expf(dl[i] * Adn) + 1e-12f;
            v[i] = fabsf(dl[i] * Bv[i] * xr[i]) + 1e-12f;
        }
#pragma unroll
        for (int p = 0; p < 8; p += 2) { v[p+1] = fmaf(c[p+1], v[p+1], v[p]); c[p+1] *= c[p]; }
        v[3] = fmaf(c[3], v[3], v[1]); c[3] *= c[1];
        v[7] = fmaf(c[7], v[7], v[5]); c[7] *= c[5];
        v[7] = fmaf(c[7], v[7], v[3]); c[7] *= c[3];
        float c7 = c[7], v7 = v[7];
#pragma unroll
        for (int h = 1; h <= 32; h <<= 1) {
            float vl = __shfl_up(v7, (unsigned)h);
            float cl = __shfl_up(c7, (unsigned)h);
            bool right = ((t & (2 * h - 1)) == (2 * h - 1));
            if (right) { v7 = fmaf(c7, v7, vl); c7 *= cl; }
        }
#pragma unroll
        for (int h = 32; h >= 1; h >>= 1) {
            float vl = __shfl_up(v7, (unsigned)h);
            float vr = __shfl_down(v7, (unsigned)h);
            bool right = ((t & (2 * h - 1)) == (2 * h - 1));
            bool left  = ((t & (2 * h - 1)) == (h - 1));
            float nv = v7;
            if (right) nv = fmaf(c7, v7, vl);
            if (left)  nv = vr;
            v7 = nv;
        }
        v[7] = v7;
        c[7] = c7;
        float tmp;
        tmp = v[7]; v[7] = fmaf(c[7], v[7], v[3]); v[3] = tmp;
        tmp = v[3]; v[3] = fmaf(c[3], v[3], v[1]); v[1] = tmp;
        tmp = v[7]; v[7] = fmaf(c[7], v[7], v[5]); v[5] = tmp;
#pragma unroll
        for (int p = 0; p < 8; p += 2) {
            tmp = v[p+1]; v[p+1] = fmaf(c[p+1], v[p+1], v[p]); v[p] = tmp;
        }
        const float4* Cp = (const float4*)(BCT + (long)(16 + n) * M_ROWS + base + l0);
        float4 c0 = Cp[0], c1 = Cp[1];
        float Cv[8] = {c0.x, c0.y, c0.z, c0.w, c1.x, c1.y, c1.z, c1.w};
#pragma unroll
        for (int i = 0; i < 8; ++i) yac[i] = fmaf(v[i], Cv[i], yac[i]);
    }

    const float Dpd = Dp[d];
#pragma unroll
    for (int i = 0; i < 8; ++i) {
        float uv = fmaf(xr[i], Dpd, yac[i]) * zsiluT[(long)d * M_ROWS + base + l0 + i];
        uT[(long)d * M_ROWS + base + l0 + i] = uv;
    }
}

// ---------------------------------------------------------------------------
// Transpose + split: uT (1536,1024) fp32 -> u interleaved bf16 (1024,1536).
// ---------------------------------------------------------------------------
__global__ __launch_bounds__(256) void transpose_split_kernel(
    const float* __restrict__ uT, ushort_t* __restrict__ u)
{
    __shared__ float T[64][65];
    const int m0 = blockIdx.x * 64;
    const int d0 = blockIdx.y * 64;
    const int c  = threadIdx.x & 63;
    const int rr = threadIdx.x >> 6;
#pragma unroll
    for (int p = 0; p < 64; p += 4)
        T[p + rr][c] = uT[(long)(d0 + p + rr) * M_ROWS + m0 + c];
    __syncthreads();
#pragma unroll
    for (int p = 0; p < 64; p += 4) {
        int rm = p + rr;
        float v = T[c][rm];
        ushort_t h, l;
        split1(v, h, l);
        int d = d0 + c;
        long off = (long)(m0 + rm) * (2 * D_INNER) + ((d >> 3) * 16 + (d & 7));
        u[off]     = h;
        u[off + 8] = l;
    }
}

// ---------------------------------------------------------------------------
extern "C" void kernel_launch(void* const* d_in, const int* in_sizes, int n_in,
                              void* d_out, int out_size, void* d_ws, size_t ws_size,
                              hipStream_t stream)
{
    (void)in_sizes; (void)n_in; (void)out_size; (void)ws_size;

    const float* x      = (const float*)d_in[0];
    const float* W_in   = (const float*)d_in[1];
    const float* conv_w = (const float*)d_in[2];
    const float* conv_b = (const float*)d_in[3];
    const float* W_x    = (const float*)d_in[4];
    const float* W_dt   = (const float*)d_in[5];
    const float* b_dt   = (const float*)d_in[6];
    const float* A_log  = (const float*)d_in[7];
    const float* Dp     = (const float*)d_in[8];
    const float* W_out  = (const float*)d_in[9];
    float* out = (float*)d_out;

    // workspace (66.6 MB, same as R8). Alias plan unchanged.
    float* ws = (float*)d_ws;
    long off = 0;
    float* xz     = ws + off; off += (long)M_ROWS * N_XZ;
    float* xz_lo  = xz;
    float* xz_hi  = xz + (long)D_INNER * M_ROWS;
    float* deltaT = xz_lo;
    float* uT     = xz_hi;
    ushort_t* u_i = (ushort_t*)xz_lo;                          // interleaved u
    float* xconvT = ws + off; off += (long)D_INNER * M_ROWS;
    float* zsiluT = ws + off; off += (long)D_INNER * M_ROWS;
    float* acc0   = ws + off; off += (long)M_ROWS * N_XDBL;
    ushort_t* w1  = (ushort_t*)(ws + off); off += (long)N_XZ * D_MODEL;    // interleaved
    ushort_t* w2  = (ushort_t*)(ws + off); off += (long)N_XDBL * D_INNER;  // interleaved
    ushort_t* xs  = (ushort_t*)(ws + off); off += (long)M_ROWS * D_MODEL;  // interleaved
    float* xcreg  = ws + off; off += (long)M_ROWS * D_INNER;               // xc / p-buf
    ushort_t* xc  = (ushort_t*)xcreg;
    float* xdreg  = ws + off; off += (long)M_ROWS * N_XDBL;                // p2 / xd
    ushort_t* xd  = (ushort_t*)xdreg;
    float* BCT    = ws + off; off += (long)2 * D_STATE * M_ROWS;

    dim3 blk(256);
    dim3 wblk(64);

    // splits: x, W_in, W_x in one launch
    hipLaunchKernelGGL(split3_kernel, dim3((SX + SW1 + SW2) / 2048), blk, 0, stream,
                       x, W_in, W_x, xs, w1, w2);
    // 1) xz = x @ W_in^T  (M=1024,N=3072,K=768), z=1, grid 768
    hipLaunchKernelGGL((gemm_mfma<1>), dim3(N_XZ / 64, M_ROWS / 64, 1), wblk, 0, stream,
                       xs, D_MODEL, w1, D_MODEL,
                       xz, xz, xz, xz, N_XZ, N_XZ, D_MODEL);
    // split W_dt -> w1 (W_in dead)
    hipLaunchKernelGGL(split_kernel, dim3((D_INNER * D_INNER) / 2048), blk, 0, stream,
                       W_dt, w1, (long)D_INNER * D_INNER);
    // 2) conv + silu
    hipLaunchKernelGGL(conv_silu_kernel, dim3((M_ROWS * D_INNER) / 256), blk, 0, stream,
                       xz, conv_w, conv_b, xconvT, zsiluT, xc);
    // 3) xconv @ W_x^T  (M=1024,N=1568,K=1536), z=3 (kc=512), grid 1200
    hipLaunchKernelGGL((gemm_mfma<3>), dim3((N_XDBL + 63) / 64, M_ROWS / 64, 3), wblk, 0, stream,
                       xc, D_INNER, w2, D_INNER,
                       acc0, xz, xdreg, xdreg, N_XDBL, N_XDBL, D_INNER / 3);
    hipLaunchKernelGGL(ep_xdbl_kernel, dim3((M_ROWS * N_XDBL) / 2048), blk, 0, stream,
                       acc0, xz, xdreg, xd, BCT);
    // split W_out -> w2 (W_x dead)
    hipLaunchKernelGGL(split_kernel, dim3((D_MODEL * D_INNER) / 2048), blk, 0, stream,
                       W_out, w2, (long)D_MODEL * D_INNER);
    // 4) W_dt @ x_dbl^T  (M=1536,N=1024,K=1536), z=4 (kc=384), grid 1536
    hipLaunchKernelGGL((gemm_mfma<4>), dim3(M_ROWS / 64, D_INNER / 64, 4), wblk, 0, stream,
                       w1, D_INNER, xd, N_XDBL,
                       acc0, xz_lo, xz_hi, xcreg, M_ROWS, M_ROWS, D_INNER / 4);
    hipLaunchKernelGGL(ep_softplus_kernel, dim3((D_INNER * M_ROWS) / 2048), blk, 0, stream,
                       acc0, xz_lo, xz_hi, xcreg, b_dt, deltaT);
    // 5) scan -> uT (xz_hi)
    hipLaunchKernelGGL(scan_kernel, dim3(BATCH * (D_INNER / 4)), blk, 0, stream,
                       deltaT, xconvT, zsiluT, BCT, A_log, Dp, uT);
    // 5b) transpose+split uT -> u interleaved (xz_lo; deltaT dead)
    hipLaunchKernelGGL(transpose_split_kernel, dim3(M_ROWS / 64, D_INNER / 64), blk, 0, stream,
                       uT, u_i);
    // 6) u @ W_out^T  (M=1024,N=768,K=1536), z=4 (kc=384), grid 768
    {
        float* p0 = acc0;
        float* p1 = acc0 + (long)M_ROWS * D_MODEL;
        float* p2 = xcreg;
        float* p3 = xcreg + (long)M_ROWS * D_MODEL;
        hipLaunchKernelGGL((gemm_mfma<4>), dim3(D_MODEL / 64, M_ROWS / 64, 4), wblk, 0, stream,
                           u_i, D_INNER, w2, D_INNER,
                           p0, p1, p2, p3, D_MODEL, D_MODEL, D_INNER / 4);
        hipLaunchKernelGGL(ep_merge_kernel, dim3((M_ROWS * D_MODEL) / 2048), blk, 0, stream,
                           p0, p1, p2, p3, out);
    }
}

// Round 10
// 297.456 us; speedup vs baseline: 1.1441x; 1.1441x over previous
//
#include <hip/hip_runtime.h>
#include <math.h>

#define D_MODEL 768
#define D_STATE 16
#define D_CONV  4
#define D_INNER 1536
#define BATCH   2
#define SEQ     512
#define M_ROWS  (BATCH * SEQ)            // 1024
#define N_XZ    (2 * D_INNER)            // 3072
#define N_XDBL  (D_INNER + 2 * D_STATE)  // 1568

typedef short  short8 __attribute__((ext_vector_type(8)));
typedef float  f32x4  __attribute__((ext_vector_type(4)));
typedef unsigned short ushort_t;
typedef ushort_t ushort8_t __attribute__((ext_vector_type(8)));

// ---- manual bf16 helpers (RNE), raw ushort storage ----
__device__ __forceinline__ ushort_t f2bf(float f) {
    unsigned int u = __float_as_uint(f);
    return (ushort_t)((u + 0x7fffu + ((u >> 16) & 1u)) >> 16);
}
__device__ __forceinline__ float bf2f(ushort_t s) {
    return __uint_as_float((unsigned int)s << 16);
}
__device__ __forceinline__ void split1(float x, ushort_t& h, ushort_t& l) {
    h = f2bf(x);
    l = f2bf(x - bf2f(h));
}
// split 8 consecutive fp32 -> interleaved [h0..h7][l0..l7] (32 B) at d
__device__ __forceinline__ void split8(const float* s, ushort_t* d) {
    ushort8_t h, l;
#pragma unroll
    for (int j = 0; j < 8; ++j) { ushort_t hh, ll; split1(s[j], hh, ll); h[j] = hh; l[j] = ll; }
    *(ushort8_t*)(d)     = h;
    *(ushort8_t*)(d + 8) = l;
}
// async global(16B/lane) -> LDS (wave-uniform base + lane*16)  [m03/m97/m104]
__device__ __forceinline__ void gld16(const ushort_t* g, void* l) {
    __builtin_amdgcn_global_load_lds((const __attribute__((address_space(1))) void*)g,
                                     (__attribute__((address_space(3))) void*)l, 16, 0, 0);
}

// ---------------------------------------------------------------------------
// Fused split: x -> xs, W_in -> w1, W_x -> w2 (interleaved h|l layout).
// ---------------------------------------------------------------------------
#define SX  (M_ROWS * D_MODEL)
#define SW1 (N_XZ * D_MODEL)
#define SW2 (N_XDBL * D_INNER)
__global__ __launch_bounds__(256) void split3_kernel(
    const float* __restrict__ x, const float* __restrict__ win,
    const float* __restrict__ wx,
    ushort_t* __restrict__ xs, ushort_t* __restrict__ w1, ushort_t* __restrict__ w2)
{
    long i = ((long)blockIdx.x * 256 + threadIdx.x) * 8;
    const float* src; ushort_t* dst; long base;
    if (i < SX)            { src = x;   dst = xs; base = i; }
    else if (i < SX + SW1) { src = win; dst = w1; base = i - SX; }
    else                   { src = wx;  dst = w2; base = i - SX - SW1; }
    float v[8];
    *(float4*)(v)     = *(const float4*)(src + base);
    *(float4*)(v + 4) = *(const float4*)(src + base + 4);
    split8(v, dst + 2 * base);
}

// single-tensor split (interleaved), 8 elems/thread
__global__ __launch_bounds__(256) void split_kernel(
    const float* __restrict__ in, ushort_t* __restrict__ outp, long n)
{
    long i = ((long)blockIdx.x * 256 + threadIdx.x) * 8;
    if (i >= n) return;
    float v[8];
    *(float4*)(v)     = *(const float4*)(in + i);
    *(float4*)(v + 4) = *(const float4*)(in + i + 4);
    split8(v, outp + 2 * i);
}

// ---------------------------------------------------------------------------
// Split-bf16 MFMA GEMM — m97-style: 256 threads, 128x128 tile, 4 waves of
// 64x64, double-buffered LDS staged via global_load_lds width=16 (async,
// cannot be serialized by the register allocator). Interleaved h|l operands.
// LDS fragment-order: slot(rg,q,lr) = rg*128 + q*16 + lr (16 B slots), where
// rg = rowgroup (row/16), q = koct*2+hl, lr = row%16 -> both the staging map
// (wave-uniform base + lane*16) and compute ds_read_b128 are conflict-free.
// XCD-compact swizzle (R8-verified). Partial z stores fp32 to Cbase+z*pstride.
// ---------------------------------------------------------------------------
__global__ __launch_bounds__(256) void gemm_lds(
    const ushort_t* __restrict__ A, int lda,   // lda = K in elems
    const ushort_t* __restrict__ B, int ldb,
    float* __restrict__ Cbase, long pstride, int ldc,
    int N, int kc)
{
    __shared__ ushort_t sm[2][2][8192];        // [buf][A|B][16 KB] = 64 KB

    const int tid  = threadIdx.x;
    const int w    = tid >> 6;
    const int lane = tid & 63;
    const int lr   = lane & 15;
    const int lq   = lane >> 4;

    const int Gx = gridDim.x, Gy = gridDim.y;
    const int T = Gx * Gy * gridDim.z;
    const int f = blockIdx.x + Gx * (blockIdx.y + Gy * blockIdx.z);
    const int g = (T & 7) ? f : ((f & 7) * (T >> 3) + (f >> 3));
    const int bx = g % Gx;
    const int by = (g / Gx) % Gy;
    const int z  = g / (Gx * Gy);
    float* __restrict__ C = Cbase + (long)z * pstride;

    const int bm = by * 128;
    const int bn = bx * 128;
    const long lda2 = 2 * (long)lda, ldb2 = 2 * (long)ldb;
    const int k0base = z * kc;

    auto stage = [&](int buf, int k0) {
#pragma unroll
        for (int i = 0; i < 4; ++i) {
            const int group = i * 4 + w;                 // wave-uniform
            const int rg = group >> 1;
            const int q  = (group & 1) * 4 + lq;         // octet*2+hl, 0..7
            const long koff = (long)k0 * 2 + (q >> 1) * 16 + (q & 1) * 8;
            const int rA = bm + rg * 16 + lr;
            int rB = bn + rg * 16 + lr; if (rB >= N) rB = N - 1;
            gld16(A + (long)rA * lda2 + koff, &sm[buf][0][group * 512]);
            gld16(B + (long)rB * ldb2 + koff, &sm[buf][1][group * 512]);
        }
    };

    f32x4 acc[4][4] = {};
    const int wm = (w & 1) * 64;
    const int wn = (w >> 1) * 64;

    stage(0, k0base);
    __syncthreads();
    const int nIter = kc >> 5;
    for (int it = 0; it < nIter; ++it) {
        const int buf = it & 1;
        if (it + 1 < nIter) stage(buf ^ 1, k0base + (it + 1) * 32);

        short8 ah[4], al[4], bh[4], bl[4];
#pragma unroll
        for (int mt = 0; mt < 4; ++mt) {
            const int sA = (((((w & 1) * 4 + mt) * 8) + lq * 2) * 16 + lr) * 8;
            ah[mt] = *(const short8*)&sm[buf][0][sA];
            al[mt] = *(const short8*)&sm[buf][0][sA + 128];
        }
#pragma unroll
        for (int nt = 0; nt < 4; ++nt) {
            const int sB = (((((w >> 1) * 4 + nt) * 8) + lq * 2) * 16 + lr) * 8;
            bh[nt] = *(const short8*)&sm[buf][1][sB];
            bl[nt] = *(const short8*)&sm[buf][1][sB + 128];
        }
#pragma unroll
        for (int mt = 0; mt < 4; ++mt)
#pragma unroll
            for (int nt = 0; nt < 4; ++nt) {
                acc[mt][nt] = __builtin_amdgcn_mfma_f32_16x16x32_bf16(al[mt], bh[nt], acc[mt][nt], 0, 0, 0);
                acc[mt][nt] = __builtin_amdgcn_mfma_f32_16x16x32_bf16(ah[mt], bl[nt], acc[mt][nt], 0, 0, 0);
                acc[mt][nt] = __builtin_amdgcn_mfma_f32_16x16x32_bf16(ah[mt], bh[nt], acc[mt][nt], 0, 0, 0);
            }
        __syncthreads();   // drains next-buf staging; frees cur buf
    }

    // C/D layout: col = lane&15, row = (lane>>4)*4 + reg  [m89/m91]
#pragma unroll
    for (int mt = 0; mt < 4; ++mt)
#pragma unroll
        for (int nt = 0; nt < 4; ++nt)
#pragma unroll
            for (int r = 0; r < 4; ++r) {
                int row = bm + wm + mt * 16 + lq * 4 + r;
                int col = bn + wn + nt * 16 + lr;
                if (col >= N) continue;
                C[(long)row * ldc + col] = acc[mt][nt][r];
            }
}

// ---------------------------------------------------------------------------
// Depthwise causal conv + bias + SiLU, fused with GEMM1 split-K merge:
// xz[r][c] = p0[r][c] + p1[r][c]. Outputs xconvT/zsiluT fp32, xc interleaved.
// ---------------------------------------------------------------------------
__global__ __launch_bounds__(256) void conv_silu_kernel(
    const float* __restrict__ p0, const float* __restrict__ p1,
    const float* __restrict__ conv_w,
    const float* __restrict__ conv_b,
    float* __restrict__ xconvT,
    float* __restrict__ zsiluT,
    ushort_t* __restrict__ xc)
{
    int idx = blockIdx.x * blockDim.x + threadIdx.x;
    if (idx >= M_ROWS * D_INNER) return;
    int d = idx % D_INNER;
    int r = idx / D_INNER;
    int l = r % SEQ;
    float acc = conv_b[d];
#pragma unroll
    for (int k = 0; k < D_CONV; ++k) {
        if (l - (D_CONV - 1) + k >= 0) {
            long o = (long)(r - (D_CONV - 1 - k)) * N_XZ + d;
            acc = fmaf(conv_w[d * D_CONV + k], p0[o] + p1[o], acc);
        }
    }
    float s = acc / (1.f + expf(-acc));
    xconvT[(long)d * M_ROWS + r] = s;
    ushort_t h, lo;
    split1(s, h, lo);
    long off = (long)r * (2 * D_INNER) + ((d >> 3) * 16 + (d & 7));
    xc[off]     = h;
    xc[off + 8] = lo;
    long oz = (long)r * N_XZ + D_INNER + d;
    float zv = p0[oz] + p1[oz];
    zsiluT[(long)d * M_ROWS + r] = zv / (1.f + expf(-zv));
}

// ---------------------------------------------------------------------------
// GEMM3 epilogue: f = sum of 3 partials (stride ps) -> xd interleaved split;
// cols >= 1536 also stored transposed fp32 into BCT.
// ---------------------------------------------------------------------------
__global__ __launch_bounds__(256) void ep_xdbl_kernel(
    const float* __restrict__ P, long ps,
    ushort_t* __restrict__ xd, float* __restrict__ BCT)
{
    long i = ((long)blockIdx.x * 256 + threadIdx.x) * 8;
    if (i >= (long)M_ROWS * N_XDBL) return;
    int row = (int)(i / N_XDBL);
    int col = (int)(i - (long)row * N_XDBL);    // multiple of 8
    float f[8];
#pragma unroll
    for (int j = 0; j < 8; ++j) f[j] = P[i + j] + P[i + j + ps] + P[i + j + 2 * ps];
    split8(f, xd + 2 * i);
    if (col >= D_INNER) {
#pragma unroll
        for (int j = 0; j < 8; ++j)
            BCT[(long)(col + j - D_INNER) * M_ROWS + row] = f[j];
    }
}

// ---------------------------------------------------------------------------
// GEMM4 epilogue: P[i] = softplus(p0+p1+p2+p3 + b_dt[row])  — in-place to p0.
// ---------------------------------------------------------------------------
__global__ __launch_bounds__(256) void ep_softplus_kernel(
    float* P, long ps, const float* __restrict__ b_dt)
{
    long i = ((long)blockIdx.x * 256 + threadIdx.x) * 8;
    if (i >= (long)D_INNER * M_ROWS) return;
    float b = b_dt[i >> 10];
    float o[8];
#pragma unroll
    for (int j = 0; j < 8; ++j) {
        float v = P[i+j] + P[i+j+ps] + P[i+j+2*ps] + P[i+j+3*ps] + b;
        o[j] = fmaxf(v, 0.f) + log1pf(expf(-fabsf(v)));
    }
    *(float4*)(P + i)     = *(float4*)(o);
    *(float4*)(P + i + 4) = *(float4*)(o + 4);
}

// ---------------------------------------------------------------------------
// GEMM6 epilogue: out = sum of 6 partials (stride ps).
// ---------------------------------------------------------------------------
__global__ __launch_bounds__(256) void ep_merge_kernel(
    const float* __restrict__ P, long ps, float* __restrict__ out)
{
    long i = ((long)blockIdx.x * 256 + threadIdx.x) * 8;
    if (i >= (long)M_ROWS * D_MODEL) return;
    float o[8];
#pragma unroll
    for (int j = 0; j < 8; ++j) {
        float v = 0.f;
#pragma unroll
        for (int z = 0; z < 6; ++z) v += P[i + j + z * ps];
        o[j] = v;
    }
    *(float4*)(out + i)     = *(float4*)(o);
    *(float4*)(out + i + 4) = *(float4*)(o + 4);
}

// ---------------------------------------------------------------------------
// Wave-per-(b,d) register scan. No LDS, no barriers. (verified R4-R9)
// ---------------------------------------------------------------------------
__global__ __launch_bounds__(256) void scan_kernel(
    const float* __restrict__ deltaT,
    const float* __restrict__ xconvT,
    const float* __restrict__ zsiluT,
    const float* __restrict__ BCT,     // (32, 1024)
    const float* __restrict__ A_log,
    const float* __restrict__ Dp,
    float* __restrict__ uT)
{
    const int bid = blockIdx.x;
    const int b   = bid / (D_INNER / 4);
    const int dg  = bid % (D_INNER / 4);
    const int tid = threadIdx.x;
    const int w   = tid >> 6;
    const int t   = tid & 63;
    const int d   = dg * 4 + w;
    const int base = b * SEQ;
    const int l0 = 8 * t;

    float dl[8], xr[8], yac[8];
#pragma unroll
    for (int i = 0; i < 8; ++i) {
        dl[i] = deltaT[(long)d * M_ROWS + base + l0 + i];
        xr[i] = xconvT[(long)d * M_ROWS + base + l0 + i];
        yac[i] = 0.f;
    }

    for (int n = 0; n < D_STATE; ++n) {
        const float Adn = -expf(A_log[d * D_STATE + n]);
        const float4* Bp = (const float4*)(BCT + (long)n * M_ROWS + base + l0);
        float4 b0 = Bp[0], b1 = Bp[1];
        float Bv[8] = {b0.x, b0.y, b0.z, b0.w, b1.x, b1.y, b1.z, b1.w};
        float c[8], v[8];
#pragma unroll
        for (int i = 0; i < 8; ++i) {
            c[i] = expf(dl[i] * Adn) + 1e-12f;
            v[i] = fabsf(dl[i] * Bv[i] * xr[i]) + 1e-12f;
        }
#pragma unroll
        for (int p = 0; p < 8; p += 2) { v[p+1] = fmaf(c[p+1], v[p+1], v[p]); c[p+1] *= c[p]; }
        v[3] = fmaf(c[3], v[3], v[1]); c[3] *= c[1];
        v[7] = fmaf(c[7], v[7], v[5]); c[7] *= c[5];
        v[7] = fmaf(c[7], v[7], v[3]); c[7] *= c[3];
        float c7 = c[7], v7 = v[7];
#pragma unroll
        for (int h = 1; h <= 32; h <<= 1) {
            float vl = __shfl_up(v7, (unsigned)h);
            float cl = __shfl_up(c7, (unsigned)h);
            bool right = ((t & (2 * h - 1)) == (2 * h - 1));
            if (right) { v7 = fmaf(c7, v7, vl); c7 *= cl; }
        }
#pragma unroll
        for (int h = 32; h >= 1; h >>= 1) {
            float vl = __shfl_up(v7, (unsigned)h);
            float vr = __shfl_down(v7, (unsigned)h);
            bool right = ((t & (2 * h - 1)) == (2 * h - 1));
            bool left  = ((t & (2 * h - 1)) == (h - 1));
            float nv = v7;
            if (right) nv = fmaf(c7, v7, vl);
            if (left)  nv = vr;
            v7 = nv;
        }
        v[7] = v7;
        c[7] = c7;
        float tmp;
        tmp = v[7]; v[7] = fmaf(c[7], v[7], v[3]); v[3] = tmp;
        tmp = v[3]; v[3] = fmaf(c[3], v[3], v[1]); v[1] = tmp;
        tmp = v[7]; v[7] = fmaf(c[7], v[7], v[5]); v[5] = tmp;
#pragma unroll
        for (int p = 0; p < 8; p += 2) {
            tmp = v[p+1]; v[p+1] = fmaf(c[p+1], v[p+1], v[p]); v[p] = tmp;
        }
        const float4* Cp = (const float4*)(BCT + (long)(16 + n) * M_ROWS + base + l0);
        float4 c0 = Cp[0], c1 = Cp[1];
        float Cv[8] = {c0.x, c0.y, c0.z, c0.w, c1.x, c1.y, c1.z, c1.w};
#pragma unroll
        for (int i = 0; i < 8; ++i) yac[i] = fmaf(v[i], Cv[i], yac[i]);
    }

    const float Dpd = Dp[d];
#pragma unroll
    for (int i = 0; i < 8; ++i) {
        float uv = fmaf(xr[i], Dpd, yac[i]) * zsiluT[(long)d * M_ROWS + base + l0 + i];
        uT[(long)d * M_ROWS + base + l0 + i] = uv;
    }
}

// ---------------------------------------------------------------------------
// Transpose + split: uT (1536,1024) fp32 -> u interleaved bf16 (1024,1536).
// ---------------------------------------------------------------------------
__global__ __launch_bounds__(256) void transpose_split_kernel(
    const float* __restrict__ uT, ushort_t* __restrict__ u)
{
    __shared__ float T[64][65];
    const int m0 = blockIdx.x * 64;
    const int d0 = blockIdx.y * 64;
    const int c  = threadIdx.x & 63;
    const int rr = threadIdx.x >> 6;
#pragma unroll
    for (int p = 0; p < 64; p += 4)
        T[p + rr][c] = uT[(long)(d0 + p + rr) * M_ROWS + m0 + c];
    __syncthreads();
#pragma unroll
    for (int p = 0; p < 64; p += 4) {
        int rm = p + rr;
        float v = T[c][rm];
        ushort_t h, l;
        split1(v, h, l);
        int d = d0 + c;
        long off = (long)(m0 + rm) * (2 * D_INNER) + ((d >> 3) * 16 + (d & 7));
        u[off]     = h;
        u[off + 8] = l;
    }
}

// ---------------------------------------------------------------------------
extern "C" void kernel_launch(void* const* d_in, const int* in_sizes, int n_in,
                              void* d_out, int out_size, void* d_ws, size_t ws_size,
                              hipStream_t stream)
{
    (void)in_sizes; (void)n_in; (void)out_size; (void)ws_size;

    const float* x      = (const float*)d_in[0];
    const float* W_in   = (const float*)d_in[1];
    const float* conv_w = (const float*)d_in[2];
    const float* conv_b = (const float*)d_in[3];
    const float* W_x    = (const float*)d_in[4];
    const float* W_dt   = (const float*)d_in[5];
    const float* b_dt   = (const float*)d_in[6];
    const float* A_log  = (const float*)d_in[7];
    const float* Dp     = (const float*)d_in[8];
    const float* W_out  = (const float*)d_in[9];
    float* out = (float*)d_out;

    // workspace ~69.7 MB. P (25.17 MB) holds all split-K partials and, later,
    // deltaT (in-place softplus over p0), uT (p1), GEMM6 partials [0:18.9MB].
    // xdreg hosts xs (pre-GEMM1), then xd (GEMM3 out), then u_i (post-scan).
    // xcreg hosts xc (conv out / GEMM3 A), then W_out split (GEMM6 B).
    float* ws = (float*)d_ws;
    long off = 0;
    float* P      = ws + off; off += 2L * M_ROWS * N_XZ;        // 6,291,456 fl
    float* xconvT = ws + off; off += (long)D_INNER * M_ROWS;
    float* zsiluT = ws + off; off += (long)D_INNER * M_ROWS;
    float* xcreg  = ws + off; off += (long)M_ROWS * D_INNER;
    float* xdreg  = ws + off; off += (long)M_ROWS * N_XDBL;
    ushort_t* w1  = (ushort_t*)(ws + off); off += (long)N_XZ * D_MODEL;
    ushort_t* w2  = (ushort_t*)(ws + off); off += (long)N_XDBL * D_INNER;
    float* BCT    = ws + off; off += (long)2 * D_STATE * M_ROWS;

    ushort_t* xs   = (ushort_t*)xdreg;          // x split (pre-GEMM1)
    ushort_t* xc   = (ushort_t*)xcreg;          // conv bf16 out
    ushort_t* xd   = (ushort_t*)xdreg;          // x_dbl split (post-GEMM3)
    ushort_t* wout = (ushort_t*)xcreg;          // W_out split (post-GEMM3)
    ushort_t* u_i  = (ushort_t*)xdreg;          // u split (post-GEMM4)
    float* deltaT  = P;                          // in-place softplus
    float* uT      = P + (long)D_INNER * M_ROWS; // p1 region

    dim3 blk(256);

    // splits: x, W_in, W_x
    hipLaunchKernelGGL(split3_kernel, dim3((SX + SW1 + SW2) / 2048), blk, 0, stream,
                       x, W_in, W_x, xs, w1, w2);
    // 1) xz = x @ W_in^T  (M=1024,N=3072,K=768), z=2 -> P[0],P[1]
    hipLaunchKernelGGL(gemm_lds, dim3(N_XZ / 128, M_ROWS / 128, 2), blk, 0, stream,
                       xs, D_MODEL, w1, D_MODEL,
                       P, (long)M_ROWS * N_XZ, N_XZ, N_XZ, D_MODEL / 2);
    // split W_dt -> w1 (W_in dead)
    hipLaunchKernelGGL(split_kernel, dim3((D_INNER * D_INNER) / 2048), blk, 0, stream,
                       W_dt, w1, (long)D_INNER * D_INNER);
    // 2) conv + silu (fuses GEMM1 partial merge)
    hipLaunchKernelGGL(conv_silu_kernel, dim3((M_ROWS * D_INNER) / 256), blk, 0, stream,
                       P, P + (long)M_ROWS * N_XZ, conv_w, conv_b, xconvT, zsiluT, xc);
    // 3) xconv @ W_x^T  (M=1024,N=1568,K=1536), z=3 -> P partials
    hipLaunchKernelGGL(gemm_lds, dim3((N_XDBL + 127) / 128, M_ROWS / 128, 3), blk, 0, stream,
                       xc, D_INNER, w2, D_INNER,
                       P, (long)M_ROWS * N_XDBL, N_XDBL, N_XDBL, D_INNER / 3);
    hipLaunchKernelGGL(ep_xdbl_kernel, dim3((M_ROWS * N_XDBL) / 2048), blk, 0, stream,
                       P, (long)M_ROWS * N_XDBL, xd, BCT);
    // split W_out -> wout (xc dead after GEMM3)
    hipLaunchKernelGGL(split_kernel, dim3((D_MODEL * D_INNER) / 2048), blk, 0, stream,
                       W_out, wout, (long)D_MODEL * D_INNER);
    // 4) W_dt @ x_dbl^T  (M=1536,N=1024,K=1536), z=4 -> P partials
    hipLaunchKernelGGL(gemm_lds, dim3(M_ROWS / 128, D_INNER / 128, 4), blk, 0, stream,
                       w1, D_INNER, xd, N_XDBL,
                       P, (long)D_INNER * M_ROWS, M_ROWS, M_ROWS, D_INNER / 4);
    hipLaunchKernelGGL(ep_softplus_kernel, dim3((D_INNER * M_ROWS) / 2048), blk, 0, stream,
                       P, (long)D_INNER * M_ROWS, b_dt);
    // 5) scan: deltaT=P (in-place) -> uT = P+p1
    hipLaunchKernelGGL(scan_kernel, dim3(BATCH * (D_INNER / 4)), blk, 0, stream,
                       deltaT, xconvT, zsiluT, BCT, A_log, Dp, uT);
    // 5b) transpose+split uT -> u_i (xdreg; xd dead after GEMM4)
    hipLaunchKernelGGL(transpose_split_kernel, dim3(M_ROWS / 64, D_INNER / 64), blk, 0, stream,
                       uT, u_i);
    // 6) u @ W_out^T  (M=1024,N=768,K=1536), z=6 -> P[0:18.9MB] (deltaT/uT dead)
    hipLaunchKernelGGL(gemm_lds, dim3(D_MODEL / 128, M_ROWS / 128, 6), blk, 0, stream,
                       u_i, D_INNER, wout, D_INNER,
                       P, (long)M_ROWS * D_MODEL, D_MODEL, D_MODEL, D_INNER / 6);
    hipLaunchKernelGGL(ep_merge_kernel, dim3((M_ROWS * D_MODEL) / 2048), blk, 0, stream,
                       P, (long)M_ROWS * D_MODEL, out);
}

// Round 11
// 291.678 us; speedup vs baseline: 1.1667x; 1.0198x over previous
//
#include <hip/hip_runtime.h>
#include <math.h>

#define D_MODEL 768
#define D_STATE 16
#define D_CONV  4
#define D_INNER 1536
#define BATCH   2
#define SEQ     512
#define M_ROWS  (BATCH * SEQ)            // 1024
#define N_XZ    (2 * D_INNER)            // 3072
#define N_XDBL  (D_INNER + 2 * D_STATE)  // 1568

typedef short  short8 __attribute__((ext_vector_type(8)));
typedef float  f32x4  __attribute__((ext_vector_type(4)));
typedef unsigned short ushort_t;
typedef ushort_t ushort8_t __attribute__((ext_vector_type(8)));

// ---- manual bf16 helpers (RNE), raw ushort storage ----
__device__ __forceinline__ ushort_t f2bf(float f) {
    unsigned int u = __float_as_uint(f);
    return (ushort_t)((u + 0x7fffu + ((u >> 16) & 1u)) >> 16);
}
__device__ __forceinline__ float bf2f(ushort_t s) {
    return __uint_as_float((unsigned int)s << 16);
}
__device__ __forceinline__ void split1(float x, ushort_t& h, ushort_t& l) {
    h = f2bf(x);
    l = f2bf(x - bf2f(h));
}
// split 8 consecutive fp32 -> interleaved [h0..h7][l0..l7] (32 B) at d
__device__ __forceinline__ void split8(const float* s, ushort_t* d) {
    ushort8_t h, l;
#pragma unroll
    for (int j = 0; j < 8; ++j) { ushort_t hh, ll; split1(s[j], hh, ll); h[j] = hh; l[j] = ll; }
    *(ushort8_t*)(d)     = h;
    *(ushort8_t*)(d + 8) = l;
}
// async global(16B/lane) -> LDS (wave-uniform base + lane*16)  [m03/m97/m104]
__device__ __forceinline__ void gld16(const ushort_t* g, void* l) {
    __builtin_amdgcn_global_load_lds((const __attribute__((address_space(1))) void*)g,
                                     (__attribute__((address_space(3))) void*)l, 16, 0, 0);
}

// ---------------------------------------------------------------------------
// Fused split: x -> xs, W_in -> w1, W_x -> w2 (interleaved h|l layout).
// ---------------------------------------------------------------------------
#define SX  (M_ROWS * D_MODEL)
#define SW1 (N_XZ * D_MODEL)
#define SW2 (N_XDBL * D_INNER)
__global__ __launch_bounds__(256) void split3_kernel(
    const float* __restrict__ x, const float* __restrict__ win,
    const float* __restrict__ wx,
    ushort_t* __restrict__ xs, ushort_t* __restrict__ w1, ushort_t* __restrict__ w2)
{
    long i = ((long)blockIdx.x * 256 + threadIdx.x) * 8;
    const float* src; ushort_t* dst; long base;
    if (i < SX)            { src = x;   dst = xs; base = i; }
    else if (i < SX + SW1) { src = win; dst = w1; base = i - SX; }
    else                   { src = wx;  dst = w2; base = i - SX - SW1; }
    float v[8];
    *(float4*)(v)     = *(const float4*)(src + base);
    *(float4*)(v + 4) = *(const float4*)(src + base + 4);
    split8(v, dst + 2 * base);
}

// ---------------------------------------------------------------------------
// Dual split: W_dt -> w1, W_out -> wout (both regions dead after GEMM3).
// ---------------------------------------------------------------------------
#define SWDT (D_INNER * D_INNER)
#define SWO  (D_MODEL * D_INNER)
__global__ __launch_bounds__(256) void split2_kernel(
    const float* __restrict__ wdt, const float* __restrict__ wo,
    ushort_t* __restrict__ w1, ushort_t* __restrict__ wout)
{
    long i = ((long)blockIdx.x * 256 + threadIdx.x) * 8;
    const float* src; ushort_t* dst; long base;
    if (i < SWDT) { src = wdt; dst = w1;   base = i; }
    else          { src = wo;  dst = wout; base = i - SWDT; }
    float v[8];
    *(float4*)(v)     = *(const float4*)(src + base);
    *(float4*)(v + 4) = *(const float4*)(src + base + 4);
    split8(v, dst + 2 * base);
}

// ---------------------------------------------------------------------------
// Split-bf16 MFMA GEMM — m97-style (verified R10): 256 threads, 128x128 tile,
// 4 waves of 64x64, double-buffered LDS staged via global_load_lds width=16.
// Interleaved h|l operands; XCD-compact swizzle; partial z -> Cbase+z*pstride.
// ---------------------------------------------------------------------------
__global__ __launch_bounds__(256) void gemm_lds(
    const ushort_t* __restrict__ A, int lda,   // lda = K in elems
    const ushort_t* __restrict__ B, int ldb,
    float* __restrict__ Cbase, long pstride, int ldc,
    int N, int kc)
{
    __shared__ ushort_t sm[2][2][8192];        // [buf][A|B][16 KB] = 64 KB

    const int tid  = threadIdx.x;
    const int w    = tid >> 6;
    const int lane = tid & 63;
    const int lr   = lane & 15;
    const int lq   = lane >> 4;

    const int Gx = gridDim.x, Gy = gridDim.y;
    const int T = Gx * Gy * gridDim.z;
    const int f = blockIdx.x + Gx * (blockIdx.y + Gy * blockIdx.z);
    const int g = (T & 7) ? f : ((f & 7) * (T >> 3) + (f >> 3));
    const int bx = g % Gx;
    const int by = (g / Gx) % Gy;
    const int z  = g / (Gx * Gy);
    float* __restrict__ C = Cbase + (long)z * pstride;

    const int bm = by * 128;
    const int bn = bx * 128;
    const long lda2 = 2 * (long)lda, ldb2 = 2 * (long)ldb;
    const int k0base = z * kc;

    auto stage = [&](int buf, int k0) {
#pragma unroll
        for (int i = 0; i < 4; ++i) {
            const int group = i * 4 + w;                 // wave-uniform
            const int rg = group >> 1;
            const int q  = (group & 1) * 4 + lq;         // octet*2+hl, 0..7
            const long koff = (long)k0 * 2 + (q >> 1) * 16 + (q & 1) * 8;
            const int rA = bm + rg * 16 + lr;
            int rB = bn + rg * 16 + lr; if (rB >= N) rB = N - 1;
            gld16(A + (long)rA * lda2 + koff, &sm[buf][0][group * 512]);
            gld16(B + (long)rB * ldb2 + koff, &sm[buf][1][group * 512]);
        }
    };

    f32x4 acc[4][4] = {};
    const int wm = (w & 1) * 64;
    const int wn = (w >> 1) * 64;

    stage(0, k0base);
    __syncthreads();
    const int nIter = kc >> 5;
    for (int it = 0; it < nIter; ++it) {
        const int buf = it & 1;
        if (it + 1 < nIter) stage(buf ^ 1, k0base + (it + 1) * 32);

        short8 ah[4], al[4], bh[4], bl[4];
#pragma unroll
        for (int mt = 0; mt < 4; ++mt) {
            const int sA = (((((w & 1) * 4 + mt) * 8) + lq * 2) * 16 + lr) * 8;
            ah[mt] = *(const short8*)&sm[buf][0][sA];
            al[mt] = *(const short8*)&sm[buf][0][sA + 128];
        }
#pragma unroll
        for (int nt = 0; nt < 4; ++nt) {
            const int sB = (((((w >> 1) * 4 + nt) * 8) + lq * 2) * 16 + lr) * 8;
            bh[nt] = *(const short8*)&sm[buf][1][sB];
            bl[nt] = *(const short8*)&sm[buf][1][sB + 128];
        }
#pragma unroll
        for (int mt = 0; mt < 4; ++mt)
#pragma unroll
            for (int nt = 0; nt < 4; ++nt) {
                acc[mt][nt] = __builtin_amdgcn_mfma_f32_16x16x32_bf16(al[mt], bh[nt], acc[mt][nt], 0, 0, 0);
                acc[mt][nt] = __builtin_amdgcn_mfma_f32_16x16x32_bf16(ah[mt], bl[nt], acc[mt][nt], 0, 0, 0);
                acc[mt][nt] = __builtin_amdgcn_mfma_f32_16x16x32_bf16(ah[mt], bh[nt], acc[mt][nt], 0, 0, 0);
            }
        __syncthreads();   // drains next-buf staging; frees cur buf
    }

    // C/D layout: col = lane&15, row = (lane>>4)*4 + reg  [m89/m91]
#pragma unroll
    for (int mt = 0; mt < 4; ++mt)
#pragma unroll
        for (int nt = 0; nt < 4; ++nt)
#pragma unroll
            for (int r = 0; r < 4; ++r) {
                int row = bm + wm + mt * 16 + lq * 4 + r;
                int col = bn + wn + nt * 16 + lr;
                if (col >= N) continue;
                C[(long)row * ldc + col] = acc[mt][nt][r];
            }
}

// ---------------------------------------------------------------------------
// Depthwise causal conv + bias + SiLU, fused with GEMM1 split-K merge.
// ---------------------------------------------------------------------------
__global__ __launch_bounds__(256) void conv_silu_kernel(
    const float* __restrict__ p0, const float* __restrict__ p1,
    const float* __restrict__ conv_w,
    const float* __restrict__ conv_b,
    float* __restrict__ xconvT,
    float* __restrict__ zsiluT,
    ushort_t* __restrict__ xc)
{
    int idx = blockIdx.x * blockDim.x + threadIdx.x;
    if (idx >= M_ROWS * D_INNER) return;
    int d = idx % D_INNER;
    int r = idx / D_INNER;
    int l = r % SEQ;
    float acc = conv_b[d];
#pragma unroll
    for (int k = 0; k < D_CONV; ++k) {
        if (l - (D_CONV - 1) + k >= 0) {
            long o = (long)(r - (D_CONV - 1 - k)) * N_XZ + d;
            acc = fmaf(conv_w[d * D_CONV + k], p0[o] + p1[o], acc);
        }
    }
    float s = acc / (1.f + expf(-acc));
    xconvT[(long)d * M_ROWS + r] = s;
    ushort_t h, lo;
    split1(s, h, lo);
    long off = (long)r * (2 * D_INNER) + ((d >> 3) * 16 + (d & 7));
    xc[off]     = h;
    xc[off + 8] = lo;
    long oz = (long)r * N_XZ + D_INNER + d;
    float zv = p0[oz] + p1[oz];
    zsiluT[(long)d * M_ROWS + r] = zv / (1.f + expf(-zv));
}

// ---------------------------------------------------------------------------
// GEMM3 epilogue: f = sum of 3 partials (stride ps) -> xd interleaved split;
// cols >= 1536 also stored transposed fp32 into BCT.
// ---------------------------------------------------------------------------
__global__ __launch_bounds__(256) void ep_xdbl_kernel(
    const float* __restrict__ P, long ps,
    ushort_t* __restrict__ xd, float* __restrict__ BCT)
{
    long i = ((long)blockIdx.x * 256 + threadIdx.x) * 8;
    if (i >= (long)M_ROWS * N_XDBL) return;
    int row = (int)(i / N_XDBL);
    int col = (int)(i - (long)row * N_XDBL);    // multiple of 8
    float f[8];
#pragma unroll
    for (int j = 0; j < 8; ++j) f[j] = P[i + j] + P[i + j + ps] + P[i + j + 2 * ps];
    split8(f, xd + 2 * i);
    if (col >= D_INNER) {
#pragma unroll
        for (int j = 0; j < 8; ++j)
            BCT[(long)(col + j - D_INNER) * M_ROWS + row] = f[j];
    }
}

// ---------------------------------------------------------------------------
// GEMM6 epilogue: out = sum of 6 partials (stride ps).
// ---------------------------------------------------------------------------
__global__ __launch_bounds__(256) void ep_merge_kernel(
    const float* __restrict__ P, long ps, float* __restrict__ out)
{
    long i = ((long)blockIdx.x * 256 + threadIdx.x) * 8;
    if (i >= (long)M_ROWS * D_MODEL) return;
    float o[8];
#pragma unroll
    for (int j = 0; j < 8; ++j) {
        float v = 0.f;
#pragma unroll
        for (int z = 0; z < 6; ++z) v += P[i + j + z * ps];
        o[j] = v;
    }
    *(float4*)(out + i)     = *(float4*)(o);
    *(float4*)(out + i + 4) = *(float4*)(o + 4);
}

// ---------------------------------------------------------------------------
// Wave-per-(b,d) register scan, now fused with the GEMM4 softplus merge:
// dl = softplus(P[..] + P[..+ps] + P[..+2ps] + P[..+3ps] + b_dt[d])  — the
// exact float ops/order ep_softplus used (bit-identical). No LDS, no barriers.
// ---------------------------------------------------------------------------
__global__ __launch_bounds__(256) void scan_kernel(
    const float* __restrict__ P, long ps,       // GEMM4 partials (1536,1024) x4
    const float* __restrict__ b_dt,
    const float* __restrict__ xconvT,
    const float* __restrict__ zsiluT,
    const float* __restrict__ BCT,              // (32, 1024)
    const float* __restrict__ A_log,
    const float* __restrict__ Dp,
    float* __restrict__ uT)
{
    const int bid = blockIdx.x;
    const int b   = bid / (D_INNER / 4);
    const int dg  = bid % (D_INNER / 4);
    const int tid = threadIdx.x;
    const int w   = tid >> 6;
    const int t   = tid & 63;
    const int d   = dg * 4 + w;
    const int base = b * SEQ;
    const int l0 = 8 * t;

    const long od = (long)d * M_ROWS + base + l0;
    const float bdt = b_dt[d];
    float dl[8], xr[8], yac[8];
#pragma unroll
    for (int i = 0; i < 8; ++i) {
        float v = P[od + i] + P[od + i + ps] + P[od + i + 2 * ps] + P[od + i + 3 * ps] + bdt;
        dl[i] = fmaxf(v, 0.f) + log1pf(expf(-fabsf(v)));   // softplus (fused)
        xr[i] = xconvT[od + i];
        yac[i] = 0.f;
    }

    for (int n = 0; n < D_STATE; ++n) {
        const float Adn = -expf(A_log[d * D_STATE + n]);
        const float4* Bp = (const float4*)(BCT + (long)n * M_ROWS + base + l0);
        float4 b0 = Bp[0], b1 = Bp[1];
        float Bv[8] = {b0.x, b0.y, b0.z, b0.w, b1.x, b1.y, b1.z, b1.w};
        float c[8], v[8];
#pragma unroll
        for (int i = 0; i < 8; ++i) {
            c[i] = expf(dl[i] * Adn) + 1e-12f;
            v[i] = fabsf(dl[i] * Bv[i] * xr[i]) + 1e-12f;
        }
#pragma unroll
        for (int p = 0; p < 8; p += 2) { v[p+1] = fmaf(c[p+1], v[p+1], v[p]); c[p+1] *= c[p]; }
        v[3] = fmaf(c[3], v[3], v[1]); c[3] *= c[1];
        v[7] = fmaf(c[7], v[7], v[5]); c[7] *= c[5];
        v[7] = fmaf(c[7], v[7], v[3]); c[7] *= c[3];
        float c7 = c[7], v7 = v[7];
#pragma unroll
        for (int h = 1; h <= 32; h <<= 1) {
            float vl = __shfl_up(v7, (unsigned)h);
            float cl = __shfl_up(c7, (unsigned)h);
            bool right = ((t & (2 * h - 1)) == (2 * h - 1));
            if (right) { v7 = fmaf(c7, v7, vl); c7 *= cl; }
        }
#pragma unroll
        for (int h = 32; h >= 1; h >>= 1) {
            float vl = __shfl_up(v7, (unsigned)h);
            float vr = __shfl_down(v7, (unsigned)h);
            bool right = ((t & (2 * h - 1)) == (2 * h - 1));
            bool left  = ((t & (2 * h - 1)) == (h - 1));
            float nv = v7;
            if (right) nv = fmaf(c7, v7, vl);
            if (left)  nv = vr;
            v7 = nv;
        }
        v[7] = v7;
        c[7] = c7;
        float tmp;
        tmp = v[7]; v[7] = fmaf(c[7], v[7], v[3]); v[3] = tmp;
        tmp = v[3]; v[3] = fmaf(c[3], v[3], v[1]); v[1] = tmp;
        tmp = v[7]; v[7] = fmaf(c[7], v[7], v[5]); v[5] = tmp;
#pragma unroll
        for (int p = 0; p < 8; p += 2) {
            tmp = v[p+1]; v[p+1] = fmaf(c[p+1], v[p+1], v[p]); v[p] = tmp;
        }
        const float4* Cp = (const float4*)(BCT + (long)(16 + n) * M_ROWS + base + l0);
        float4 c0 = Cp[0], c1 = Cp[1];
        float Cv[8] = {c0.x, c0.y, c0.z, c0.w, c1.x, c1.y, c1.z, c1.w};
#pragma unroll
        for (int i = 0; i < 8; ++i) yac[i] = fmaf(v[i], Cv[i], yac[i]);
    }

    const float Dpd = Dp[d];
#pragma unroll
    for (int i = 0; i < 8; ++i) {
        float uv = fmaf(xr[i], Dpd, yac[i]) * zsiluT[od + i];
        uT[od + i] = uv;
    }
}

// ---------------------------------------------------------------------------
// Transpose + split: uT (1536,1024) fp32 -> u interleaved bf16 (1024,1536).
// ---------------------------------------------------------------------------
__global__ __launch_bounds__(256) void transpose_split_kernel(
    const float* __restrict__ uT, ushort_t* __restrict__ u)
{
    __shared__ float T[64][65];
    const int m0 = blockIdx.x * 64;
    const int d0 = blockIdx.y * 64;
    const int c  = threadIdx.x & 63;
    const int rr = threadIdx.x >> 6;
#pragma unroll
    for (int p = 0; p < 64; p += 4)
        T[p + rr][c] = uT[(long)(d0 + p + rr) * M_ROWS + m0 + c];
    __syncthreads();
#pragma unroll
    for (int p = 0; p < 64; p += 4) {
        int rm = p + rr;
        float v = T[c][rm];
        ushort_t h, l;
        split1(v, h, l);
        int d = d0 + c;
        long off = (long)(m0 + rm) * (2 * D_INNER) + ((d >> 3) * 16 + (d & 7));
        u[off]     = h;
        u[off + 8] = l;
    }
}

// ---------------------------------------------------------------------------
extern "C" void kernel_launch(void* const* d_in, const int* in_sizes, int n_in,
                              void* d_out, int out_size, void* d_ws, size_t ws_size,
                              hipStream_t stream)
{
    (void)in_sizes; (void)n_in; (void)out_size; (void)ws_size;

    const float* x      = (const float*)d_in[0];
    const float* W_in   = (const float*)d_in[1];
    const float* conv_w = (const float*)d_in[2];
    const float* conv_b = (const float*)d_in[3];
    const float* W_x    = (const float*)d_in[4];
    const float* W_dt   = (const float*)d_in[5];
    const float* b_dt   = (const float*)d_in[6];
    const float* A_log  = (const float*)d_in[7];
    const float* Dp     = (const float*)d_in[8];
    const float* W_out  = (const float*)d_in[9];
    float* out = (float*)d_out;

    // workspace ~69.7 MB (same as R10). Liveness plan:
    //  P (25.2 MB): G1 p0/p1 -> G3 p0..p2 -> G4 p0..p3 (scan reads them live,
    //    fused softplus) -> after scan dead -> u_i [0:6.3MB] + G6 p0..p5
    //    [6.3:25.2MB] (exactly fills P).
    //  xdreg: xs (pre-G1) -> xd (G3 out, G4 B) -> uT (scan out).
    //  xcreg: xc (conv out, G3 A) -> wout (W_out split, G6 B).
    float* ws = (float*)d_ws;
    long off = 0;
    float* P      = ws + off; off += 2L * M_ROWS * N_XZ;        // 6,291,456 fl
    float* xconvT = ws + off; off += (long)D_INNER * M_ROWS;
    float* zsiluT = ws + off; off += (long)D_INNER * M_ROWS;
    float* xcreg  = ws + off; off += (long)M_ROWS * D_INNER;
    float* xdreg  = ws + off; off += (long)M_ROWS * N_XDBL;
    ushort_t* w1  = (ushort_t*)(ws + off); off += (long)N_XZ * D_MODEL;
    ushort_t* w2  = (ushort_t*)(ws + off); off += (long)N_XDBL * D_INNER;
    float* BCT    = ws + off; off += (long)2 * D_STATE * M_ROWS;

    ushort_t* xs   = (ushort_t*)xdreg;          // x split (pre-GEMM1)
    ushort_t* xc   = (ushort_t*)xcreg;          // conv bf16 out (GEMM3 A)
    ushort_t* xd   = (ushort_t*)xdreg;          // x_dbl split (GEMM4 B)
    ushort_t* wout = (ushort_t*)xcreg;          // W_out split (GEMM6 B)
    float* uT      = xdreg;                     // scan out (xd dead post-G4)
    ushort_t* u_i  = (ushort_t*)P;              // u split (P dead post-scan)
    float* P6      = P + (long)M_ROWS * N_XZ / 2;  // GEMM6 partials (+1,572,864 fl)

    const long psG4 = (long)D_INNER * M_ROWS;

    dim3 blk(256);

    // 1) splits: x, W_in, W_x
    hipLaunchKernelGGL(split3_kernel, dim3((SX + SW1 + SW2) / 2048), blk, 0, stream,
                       x, W_in, W_x, xs, w1, w2);
    // 2) xz = x @ W_in^T  (M=1024,N=3072,K=768), z=2 -> P[0],P[1]
    hipLaunchKernelGGL(gemm_lds, dim3(N_XZ / 128, M_ROWS / 128, 2), blk, 0, stream,
                       xs, D_MODEL, w1, D_MODEL,
                       P, (long)M_ROWS * N_XZ, N_XZ, N_XZ, D_MODEL / 2);
    // 3) conv + silu (fuses GEMM1 partial merge)
    hipLaunchKernelGGL(conv_silu_kernel, dim3((M_ROWS * D_INNER) / 256), blk, 0, stream,
                       P, P + (long)M_ROWS * N_XZ, conv_w, conv_b, xconvT, zsiluT, xc);
    // 4) xconv @ W_x^T  (M=1024,N=1568,K=1536), z=3 -> P partials
    hipLaunchKernelGGL(gemm_lds, dim3((N_XDBL + 127) / 128, M_ROWS / 128, 3), blk, 0, stream,
                       xc, D_INNER, w2, D_INNER,
                       P, (long)M_ROWS * N_XDBL, N_XDBL, N_XDBL, D_INNER / 3);
    // 5) merge partials -> xd split + BCT
    hipLaunchKernelGGL(ep_xdbl_kernel, dim3((M_ROWS * N_XDBL) / 2048), blk, 0, stream,
                       P, (long)M_ROWS * N_XDBL, xd, BCT);
    // 6) dual split: W_dt -> w1, W_out -> wout (both regions now dead)
    hipLaunchKernelGGL(split2_kernel, dim3((SWDT + SWO) / 2048), blk, 0, stream,
                       W_dt, W_out, w1, wout);
    // 7) W_dt @ x_dbl^T  (M=1536,N=1024,K=1536), z=4 -> P partials
    hipLaunchKernelGGL(gemm_lds, dim3(M_ROWS / 128, D_INNER / 128, 4), blk, 0, stream,
                       w1, D_INNER, xd, N_XDBL,
                       P, psG4, M_ROWS, M_ROWS, D_INNER / 4);
    // 8) scan (fused softplus merge of the 4 partials) -> uT (xdreg)
    hipLaunchKernelGGL(scan_kernel, dim3(BATCH * (D_INNER / 4)), blk, 0, stream,
                       P, psG4, b_dt, xconvT, zsiluT, BCT, A_log, Dp, uT);
    // 9) transpose+split uT -> u_i (P base; P partials dead after scan)
    hipLaunchKernelGGL(transpose_split_kernel, dim3(M_ROWS / 64, D_INNER / 64), blk, 0, stream,
                       uT, u_i);
    // 10) u @ W_out^T  (M=1024,N=768,K=1536), z=6 -> P6
    hipLaunchKernelGGL(gemm_lds, dim3(D_MODEL / 128, M_ROWS / 128, 6), blk, 0, stream,
                       u_i, D_INNER, wout, D_INNER,
                       P6, (long)M_ROWS * D_MODEL, D_MODEL, D_MODEL, D_INNER / 6);
    // 11) merge -> out
    hipLaunchKernelGGL(ep_merge_kernel, dim3((M_ROWS * D_MODEL) / 2048), blk, 0, stream,
                       P6, (long)M_ROWS * D_MODEL, out);
}